// Round 5
// baseline (29.882 us; speedup 1.0000x reference)
//
#include <hip/hip_runtime.h>

typedef float f4 __attribute__((ext_vector_type(4)));

#define NCLS 20
#define BPB 4                      // batches per block
#define FPB 1470                   // floats per batch = 30*49
#define LDSF (BPB * FPB)           // 5880 floats = 23.52 KB -> 6 blocks/CU
#define LDSV4 (LDSF / 4)           // 1470 float4

__global__ __launch_bounds__(256) void yolo_kernel(const float* __restrict__ x,
                                                   float* __restrict__ boxes,
                                                   float* __restrict__ scores,
                                                   float* __restrict__ idxs) {
    __shared__ float lds[LDSF];
    const int blk = blockIdx.x;
    const int tid = threadIdx.x;

    // ---- global -> LDS: contiguous nontemporal dwordx4 stream ----
    const f4* src = reinterpret_cast<const f4*>(x) + (size_t)blk * LDSV4;
    f4* dst = reinterpret_cast<f4*>(lds);
    #pragma unroll
    for (int k = 0; k < 6; ++k) {
        int i = tid + k * 256;
        if (i < LDSV4) dst[i] = __builtin_nontemporal_load(src + i);
    }
    __syncthreads();

    // ---- compute: 4 batches * 49 cells = 196 cells, exactly one pass ----
    const int c = tid;
    if (c < BPB * 49) {
        int bl = c / 49;
        int cell = c - bl * 49;
        int row = cell / 7;
        int col = cell - row * 7;
        const float* xb = lds + bl * FPB + cell;

        float cls[NCLS];
        #pragma unroll
        for (int i = 0; i < NCLS; ++i) cls[i] = xb[(10 + i) * 49];

        float gx = (float)col;   // gi[0] = column index
        float gy = (float)row;   // gi[1] = row index
        int batch = blk * BPB + bl;

        #pragma unroll
        for (int b = 0; b < 2; ++b) {
            float d0   = xb[(b * 5 + 0) * 49];
            float d1   = xb[(b * 5 + 1) * 49];
            float d2   = xb[(b * 5 + 2) * 49];
            float d3   = xb[(b * 5 + 3) * 49];
            float conf = xb[(b * 5 + 4) * 49];

            // weighted max + first-occurrence argmax (strict >)
            float best = cls[0] * conf;
            int bi = 0;
            #pragma unroll
            for (int i = 1; i < NCLS; ++i) {
                float w = cls[i] * conf;
                if (w > best) { best = w; bi = i; }
            }

            float cxv = (d0 + gx) / 7.0f;
            float cyv = (d1 + gy) / 7.0f;
            float hx = d2 * 0.5f;
            float hy = d3 * 0.5f;

            size_t obase = (size_t)batch * 98 + b * 49 + cell;
            f4 bx;
            bx.x = cxv - hx; bx.y = cyv - hy; bx.z = cxv + hx; bx.w = cyv + hy;
            __builtin_nontemporal_store(bx, reinterpret_cast<f4*>(boxes + obase * 4));
            __builtin_nontemporal_store(best, scores + obase);
            __builtin_nontemporal_store((float)bi, idxs + obase);
        }
    }
}

extern "C" void kernel_launch(void* const* d_in, const int* in_sizes, int n_in,
                              void* d_out, int out_size, void* d_ws, size_t ws_size,
                              hipStream_t stream) {
    const float* x = (const float*)d_in[0];
    int B = in_sizes[0] / FPB;   // 16384

    float* out    = (float*)d_out;
    float* boxes  = out;                      // B*98*4
    float* scores = out + (size_t)B * 98 * 4; // B*98
    float* idxs   = scores + (size_t)B * 98;  // B*98

    int grid = B / BPB;  // 4096 blocks
    hipLaunchKernelGGL(yolo_kernel, dim3(grid), dim3(256), 0, stream,
                       x, boxes, scores, idxs);
}

// Round 6
// 25.618 us; speedup vs baseline: 1.1664x; 1.1664x over previous
//
#include <hip/hip_runtime.h>

#define NCLS 20
#define BPB 2                      // batches per block
#define FPB 1470                   // floats per batch = 30*49
#define LDSF (BPB * FPB)           // 2940 floats = 11.76 KB -> 8 blocks/CU (thread-limited)
#define LDSV4 (LDSF / 4)           // 735 float4

__global__ __launch_bounds__(256) void yolo_kernel(const float* __restrict__ x,
                                                   float* __restrict__ boxes,
                                                   float* __restrict__ scores,
                                                   float* __restrict__ idxs) {
    __shared__ float lds[LDSF];
    const int blk = blockIdx.x;
    const int tid = threadIdx.x;

    // ---- global -> LDS: contiguous dwordx4 stream (735 vec4 per block) ----
    const float4* src = reinterpret_cast<const float4*>(x) + (size_t)blk * LDSV4;
    float4* dst = reinterpret_cast<float4*>(lds);
    #pragma unroll
    for (int k = 0; k < 3; ++k) {
        int i = tid + k * 256;
        if (i < LDSV4) dst[i] = src[i];
    }
    __syncthreads();

    // ---- compute: 2 batches * 49 cells = 98 cells, single pass ----
    const int c = tid;
    if (c < BPB * 49) {
        int bl = c / 49;
        int cell = c - bl * 49;
        int row = cell / 7;
        int col = cell - row * 7;
        const float* xb = lds + bl * FPB + cell;

        float cls[NCLS];
        #pragma unroll
        for (int i = 0; i < NCLS; ++i) cls[i] = xb[(10 + i) * 49];

        float gx = (float)col;   // gi[0] = column index
        float gy = (float)row;   // gi[1] = row index
        int batch = blk * BPB + bl;

        #pragma unroll
        for (int b = 0; b < 2; ++b) {
            float d0   = xb[(b * 5 + 0) * 49];
            float d1   = xb[(b * 5 + 1) * 49];
            float d2   = xb[(b * 5 + 2) * 49];
            float d3   = xb[(b * 5 + 3) * 49];
            float conf = xb[(b * 5 + 4) * 49];

            // weighted max + first-occurrence argmax (strict >)
            float best = cls[0] * conf;
            int bi = 0;
            #pragma unroll
            for (int i = 1; i < NCLS; ++i) {
                float w = cls[i] * conf;
                if (w > best) { best = w; bi = i; }
            }

            float cxv = (d0 + gx) / 7.0f;
            float cyv = (d1 + gy) / 7.0f;
            float hx = d2 * 0.5f;
            float hy = d3 * 0.5f;

            size_t obase = (size_t)batch * 98 + b * 49 + cell;
            *reinterpret_cast<float4*>(boxes + obase * 4) =
                make_float4(cxv - hx, cyv - hy, cxv + hx, cyv + hy);
            scores[obase] = best;
            idxs[obase]   = (float)bi;
        }
    }
}

extern "C" void kernel_launch(void* const* d_in, const int* in_sizes, int n_in,
                              void* d_out, int out_size, void* d_ws, size_t ws_size,
                              hipStream_t stream) {
    const float* x = (const float*)d_in[0];
    int B = in_sizes[0] / FPB;   // 16384

    float* out    = (float*)d_out;
    float* boxes  = out;                      // B*98*4
    float* scores = out + (size_t)B * 98 * 4; // B*98
    float* idxs   = scores + (size_t)B * 98;  // B*98

    int grid = B / BPB;  // 8192 blocks
    hipLaunchKernelGGL(yolo_kernel, dim3(grid), dim3(256), 0, stream,
                       x, boxes, scores, idxs);
}